// Round 7
// baseline (996.244 us; speedup 1.0000x reference)
//
#include <hip/hip_runtime.h>
#include <math.h>

// ---------------- problem constants ----------------
#define BB 4
#define SS 2048
#define DD 2048
#define HH 16
#define NOPE 128
#define ROPE 64
#define VD 128
#define QKD 192         // NOPE+ROPE
#define KVR 512
#define NPAD 640        // KVR+ROPE padded to 128 multiple
#define ROWS (BB*SS)    // 8192
// log2(e) / sqrt(192), folded into Q at rope time
#define SCL2 0.1041216338380858f

typedef __attribute__((ext_vector_type(8))) short bf16x8;
typedef __attribute__((ext_vector_type(4))) float f32x4;
typedef unsigned short bfu;
typedef __attribute__((address_space(1))) const void GV;
typedef __attribute__((address_space(3))) void LV;

__device__ __forceinline__ float bf2f(unsigned int u) {
    unsigned int i = u << 16; float f; __builtin_memcpy(&f, &i, 4); return f;
}
__device__ __forceinline__ unsigned int f2bf(float f) {
    unsigned int i; __builtin_memcpy(&i, &f, 4);
    return (i + 0x7fffu + ((i >> 16) & 1u)) >> 16;
}
__device__ __forceinline__ unsigned int cvt_pk_bf16(float lo, float hi) {
    unsigned int r;
    asm("v_cvt_pk_bf16_f32 %0, %1, %2" : "=v"(r) : "v"(lo), "v"(hi));
    return r;
}

// ---------------- cast fp32 -> bf16 (x input) ----------------
__global__ void cast_f32_bf16(const float* __restrict__ src, bfu* __restrict__ dst,
                              long n_src, long n_dst) {
    long i = (long)blockIdx.x * blockDim.x + threadIdx.x;   // one float4 each
    if (i * 4 >= n_dst) return;
    unsigned int lo = 0, hi = 0;
    if (i * 4 < n_src) {
        float4 v = ((const float4*)src)[i];
        lo = f2bf(v.x) | (f2bf(v.y) << 16);
        hi = f2bf(v.z) | (f2bf(v.w) << 16);
    }
    ((uint2*)dst)[i] = make_uint2(lo, hi);
}

// ---------------- fused weight casts (wq | wkv_a(+pad) | wkv_b | wo) ----------------
__global__ void cast_weights(const float* __restrict__ wq, const float* __restrict__ wa,
                             const float* __restrict__ wb, const float* __restrict__ wo,
                             bfu* __restrict__ dq, bfu* __restrict__ da,
                             bfu* __restrict__ db, bfu* __restrict__ dwo) {
    long i = (long)blockIdx.x * 256 + threadIdx.x;   // one float4 each
    const float* src; bfu* dst; long off, n_src;
    if (i < 1572864L)        { src = wq; dst = dq;  off = i;            n_src = 1572864L; }
    else if (i < 1900544L)   { src = wa; dst = da;  off = i - 1572864L; n_src = 294912L;  }
    else if (i < 2424832L)   { src = wb; dst = db;  off = i - 1900544L; n_src = 524288L;  }
    else if (i < 3473408L)   { src = wo; dst = dwo; off = i - 2424832L; n_src = 1048576L; }
    else return;
    unsigned int lo = 0, hi = 0;
    if (off < n_src) {
        float4 v = ((const float4*)src)[off];
        lo = f2bf(v.x) | (f2bf(v.y) << 16);
        hi = f2bf(v.z) | (f2bf(v.w) << 16);
    }
    ((uint2*)dst)[off] = make_uint2(lo, hi);
}

// ---------------- 128x128 tile bf16 GEMM, C = A[M,K] @ Bt[N,K]^T ----------------
template <int OUTF32>
__global__ void __launch_bounds__(256)
gemm_bt(const bfu* __restrict__ A, const bfu* __restrict__ Bt,
        void* __restrict__ Cv, int N, int K) {
    __shared__ __align__(16) char lds[32768];
    char* AsB = lds;
    char* BsB = lds + 16384;
    const int tid  = threadIdx.x;
    const int lane = tid & 63;
    const int wid  = tid >> 6;
    const int wr   = wid >> 1, wc = wid & 1;
    const long m0 = (long)blockIdx.y * 128;
    const long n0 = (long)blockIdx.x * 128;

    f32x4 acc[4][4] = {};

    const int lr = lane >> 3;            // row within 8-row stripe
    const int SB = (lane & 7) << 4;      // 16B slot within 128B row

    for (int k0 = 0; k0 < K; k0 += 64) {
        __syncthreads();
#pragma unroll
        for (int i = 0; i < 4; ++i) {
            int rb = wid * 32 + i * 8;   // wave-uniform row base
            int R  = rb + lr;
            int c  = (SB ^ ((R & 7) << 4)) >> 1;   // pre-swizzled source column
            const bfu* gA = A  + (m0 + R) * (long)K + k0 + c;
            const bfu* gB = Bt + (n0 + R) * (long)K + k0 + c;
            __builtin_amdgcn_global_load_lds((GV*)gA, (LV*)(AsB + rb * 128), 16, 0, 0);
            __builtin_amdgcn_global_load_lds((GV*)gB, (LV*)(BsB + rb * 128), 16, 0, 0);
        }
        __syncthreads();
#pragma unroll
        for (int kk = 0; kk < 2; ++kk) {
            bf16x8 av[4], bv[4];
            const int cb = kk * 64 + ((lane >> 4) << 4);
#pragma unroll
            for (int m = 0; m < 4; ++m) {
                int R = wr * 64 + m * 16 + (lane & 15);
                av[m] = *(const bf16x8*)(AsB + R * 128 + (cb ^ ((R & 7) << 4)));
            }
#pragma unroll
            for (int n = 0; n < 4; ++n) {
                int R = wc * 64 + n * 16 + (lane & 15);
                bv[n] = *(const bf16x8*)(BsB + R * 128 + (cb ^ ((R & 7) << 4)));
            }
#pragma unroll
            for (int m = 0; m < 4; ++m)
#pragma unroll
                for (int n = 0; n < 4; ++n)
                    acc[m][n] = __builtin_amdgcn_mfma_f32_16x16x32_bf16(av[m], bv[n], acc[m][n], 0, 0, 0);
        }
    }

    const int cr = (lane >> 4) << 2;
    const int cc = lane & 15;
#pragma unroll
    for (int m = 0; m < 4; ++m)
#pragma unroll
        for (int n = 0; n < 4; ++n)
#pragma unroll
            for (int r = 0; r < 4; ++r) {
                long row = m0 + wr * 64 + m * 16 + cr + r;
                long col = n0 + wc * 64 + n * 16 + cc;
                if (OUTF32) ((float*)Cv)[row * N + col] = acc[m][n][r];
                else        ((bfu*)Cv)[row * N + col] = (bfu)f2bf(acc[m][n][r]);
            }
}

// ---------------- RoPE on q_pe + rearrange q -> [b][h][s][192], pre-scaled ----------------
__global__ void rope_q(const bfu* __restrict__ q1, bfu* __restrict__ qr,
                       const float* __restrict__ fc, const float* __restrict__ fs) {
    long t = (long)blockIdx.x * 256 + threadIdx.x;   // one (e,o) pair
    const long total = (long)BB * HH * SS * 96;
    if (t >= total) return;
    int  p  = (int)(t % 96);
    long r  = t / 96;
    int  h  = (int)(r % HH);
    long bs = r / HH;                 // b*S + s
    int  s  = (int)(bs % SS);
    long b_ = bs / SS;
    unsigned int v = *(const unsigned int*)(q1 + bs * (HH * QKD) + h * QKD + 2 * p);
    float e = bf2f(v & 0xffff), o = bf2f(v >> 16);
    if (p >= 64) {
        int i = p - 64;
        float c = fc[s * 32 + i], sn = fs[s * 32 + i];
        float ye = e * c - o * sn;
        float yo = e * sn + o * c;
        e = ye; o = yo;
    }
    e *= SCL2; o *= SCL2;             // fold softmax scale + log2(e) into Q
    unsigned int out = f2bf(e) | (f2bf(o) << 16);
    *(unsigned int*)(qr + ((b_ * HH + h) * SS + s) * (long)QKD + 2 * p) = out;
}

// ---------------- RMSNorm(kv_c) + RoPE(k_pe), one block per (b,s) row ----------------
__global__ void __launch_bounds__(256)
rms_rope_kv(const bfu* __restrict__ kv1, const float* __restrict__ wn,
            bfu* __restrict__ kvc, bfu* __restrict__ kpe,
            const float* __restrict__ fc, const float* __restrict__ fs) {
    const int row = blockIdx.x;            // b*S + s
    const int t   = threadIdx.x;
    const int s   = row & (SS - 1);
    const long base = (long)row * NPAD;
    unsigned int v = *(const unsigned int*)(kv1 + base + 2 * t);
    float a = bf2f(v & 0xffff), c2 = bf2f(v >> 16);
    float ssum = a * a + c2 * c2;
#pragma unroll
    for (int d = 1; d < 64; d <<= 1) ssum += __shfl_xor(ssum, d);
    __shared__ float red[4];
    const int lane = t & 63, w = t >> 6;
    if (lane == 0) red[w] = ssum;
    __syncthreads();
    float tot = red[0] + red[1] + red[2] + red[3];
    float scale = rsqrtf(tot * (1.0f / 512.0f) + 1e-6f);
    float w0 = wn[2 * t], w1 = wn[2 * t + 1];
    unsigned int out = f2bf(a * scale * w0) | (f2bf(c2 * scale * w1) << 16);
    *(unsigned int*)(kvc + (long)row * KVR + 2 * t) = out;
    if (t < 32) {
        unsigned int pv = *(const unsigned int*)(kv1 + base + KVR + 2 * t);
        float e = bf2f(pv & 0xffff), o = bf2f(pv >> 16);
        float cc = fc[s * 32 + t], sn = fs[s * 32 + t];
        unsigned int po = f2bf(e * cc - o * sn) | (f2bf(e * sn + o * cc) << 16);
        *(unsigned int*)(kpe + (long)row * ROPE + 2 * t) = po;
    }
}

// ---------------- K assembly: kall[b][h][s][192] = [k_nope | k_pe] ----------------
__global__ void repack_k(const bfu* __restrict__ kvb2, const bfu* __restrict__ kpe,
                         bfu* __restrict__ kall) {
    long t = (long)blockIdx.x * 256 + threadIdx.x;  // one 8-elem chunk
    const long total = (long)BB * HH * SS * 24;
    if (t >= total) return;
    int  ch = (int)(t % 24);
    long r  = t / 24;
    int  s  = (int)(r % SS);
    long r2 = r / SS;
    int  h  = (int)(r2 % HH);
    long b_ = r2 / HH;
    bf16x8 val;
    if (ch < 16)
        val = *(const bf16x8*)(kvb2 + (b_ * SS + s) * 4096 + h * 256 + ch * 8);
    else
        val = *(const bf16x8*)(kpe + (b_ * SS + s) * (long)ROPE + (ch - 16) * 8);
    *(bf16x8*)(kall + ((b_ * HH + h) * SS + s) * (long)QKD + ch * 8) = val;
}

// ---------------- V transpose via LDS tile: vt[b][h][v][s] ----------------
__global__ void __launch_bounds__(256)
transpose_v2(const bfu* __restrict__ kvb2, bfu* __restrict__ vt) {
    __shared__ __align__(16) char tile[64 * 256];   // 16 KB
    const int tid = threadIdx.x;
    const int bid = blockIdx.x;          // 64 bh * 32 s-tiles
    const int st  = bid & 31;
    const int bh  = bid >> 5;
    const int h   = bh & 15;
    const long b_ = bh >> 4;
    const long sbase = b_ * SS + st * 64;
#pragma unroll
    for (int i = 0; i < 4; ++i) {
        int idx = i * 256 + tid;
        int row = idx >> 4;
        int ch  = (idx & 15) ^ ((row >> 3) & 7);
        const bfu* src = kvb2 + (sbase + row) * 4096 + h * 256 + 128 + ch * 8;
        __builtin_amdgcn_global_load_lds((GV*)src, (LV*)(tile + idx * 16), 16, 0, 0);
    }
    __syncthreads();
#pragma unroll
    for (int i = 0; i < 4; ++i) {
        int idx = i * 256 + tid;
        int sc = idx & 7;            // s-chunk of 8
        int v  = (idx >> 3) & 127;
        bfu tmp[8];
#pragma unroll
        for (int k = 0; k < 8; ++k) {
            int row = sc * 8 + k;
            tmp[k] = *(const bfu*)(tile + row * 256 + (((v >> 3) ^ ((row >> 3) & 7)) << 4) + (v & 7) * 2);
        }
        *(bf16x8*)(vt + ((long)bh * VD + v) * SS + st * 64 + sc * 8) = *(bf16x8*)tmp;
    }
}

// ---------------- flash causal attention v7 (R2 structure, occupancy-pinned) ----------------
// 4 waves x 32 q-rows, KV tile 64 LDS-staged from compact kall/vt (L3-resident).
// v7: launch_bounds(256,3) pins 3 waves/SIMD; cvt_pk P-pack; hoisted LDS offsets.
template <bool MASKED>
__device__ __forceinline__ void attn_tile64(
    const char* kbuf, const char* vbuf, char* pwb,
    const int (&koff)[6], const int (&voff)[2], int poff,
    const bf16x8 (&qf)[6], f32x4 (&accv)[8],
    float& ms, float& ls, int kv0, int qa, int ql, int kg, int lane) {
    // ---- QK^T from LDS: C[kv][q] ----
    f32x4 sc[4] = {};
    __builtin_amdgcn_s_setprio(1);
#pragma unroll
    for (int j = 0; j < 4; ++j)
#pragma unroll
        for (int d = 0; d < 6; ++d) {
            bf16x8 kf = *(const bf16x8*)(kbuf + koff[d] + j * (16 * 384));
            sc[j] = __builtin_amdgcn_mfma_f32_16x16x32_bf16(kf, qf[d], sc[j], 0, 0, 0);
        }
    __builtin_amdgcn_s_setprio(0);
    // ---- online softmax (q = ql lane-local column; Q pre-scaled, exp2 domain) ----
    float p[4][4];
    float mx = -1e30f;
#pragma unroll
    for (int j = 0; j < 4; ++j)
#pragma unroll
        for (int r = 0; r < 4; ++r) {
            float s = sc[j][r];
            if (MASKED) {
                int kv = kv0 + j * 16 + kg * 4 + r;
                s = (kv > qa) ? -1e30f : s;
            }
            p[j][r] = s;
            mx = fmaxf(mx, s);
        }
    mx = fmaxf(mx, __shfl_xor(mx, 16));
    mx = fmaxf(mx, __shfl_xor(mx, 32));
    float rs = 0.f;
    if (__all(mx <= ms)) {            // defer-max: running max unchanged, no rescale
#pragma unroll
        for (int j = 0; j < 4; ++j)
#pragma unroll
            for (int r = 0; r < 4; ++r) {
                float e = exp2f(p[j][r] - ms);
                p[j][r] = e;
                rs += e;
            }
        rs += __shfl_xor(rs, 16);
        rs += __shfl_xor(rs, 32);
        ls += rs;
    } else {
        float mn = fmaxf(ms, mx);
        float al = exp2f(ms - mn);
        ms = mn;
#pragma unroll
        for (int j = 0; j < 4; ++j)
#pragma unroll
            for (int r = 0; r < 4; ++r) {
                float e = exp2f(p[j][r] - mn);
                p[j][r] = e;
                rs += e;
            }
        rs += __shfl_xor(rs, 16);
        rs += __shfl_xor(rs, 32);
        ls = ls * al + rs;
        float alT[4];
#pragma unroll
        for (int r = 0; r < 4; ++r)
            alT[r] = __shfl(al, (lane & 48) + kg * 4 + r);
#pragma unroll
        for (int v8 = 0; v8 < 8; ++v8)
#pragma unroll
            for (int r = 0; r < 4; ++r)
                accv[v8][r] *= alT[r];
    }
    // ---- repack P -> wave LDS [16 q][64 kv], swizzled; cvt_pk packing ----
#pragma unroll
    for (int j = 0; j < 4; ++j) {
        uint2 u;
        u.x = cvt_pk_bf16(p[j][0], p[j][1]);
        u.y = cvt_pk_bf16(p[j][2], p[j][3]);
        int slot = (2 * j + (kg >> 1)) ^ (ql & 7);
        *(uint2*)(pwb + ql * 128 + slot * 16 + (kg & 1) * 8) = u;
    }
    asm volatile("s_waitcnt lgkmcnt(0)" ::: "memory");
    // ---- PV from LDS: out[q][v] += P V ----
    __builtin_amdgcn_s_setprio(1);
#pragma unroll
    for (int t2 = 0; t2 < 2; ++t2) {
        bf16x8 pa = *(const bf16x8*)(pwb + poff + ((t2 * 4 + kg) ^ (ql & 7)) * 16);
#pragma unroll
        for (int v8 = 0; v8 < 8; ++v8) {
            bf16x8 vf = *(const bf16x8*)(vbuf + voff[t2] + v8 * 2048);
            accv[v8] = __builtin_amdgcn_mfma_f32_16x16x32_bf16(pa, vf, accv[v8], 0, 0, 0);
        }
    }
    __builtin_amdgcn_s_setprio(0);
}

__global__ void __launch_bounds__(256, 3)
attn(const bfu* __restrict__ qr, const bfu* __restrict__ kall,
     const bfu* __restrict__ vt, bfu* __restrict__ ao) {
    __shared__ __align__(16) char kbuf[64 * 384];    // 24576
    __shared__ __align__(16) char vbuf[128 * 128];   // 16384
    __shared__ __align__(16) char pbuf[4][2048];     //  8192
    const int tid  = threadIdx.x;
    const int lane = tid & 63;
    const int w    = tid >> 6;
    const int ql   = lane & 15;
    const int kg   = lane >> 4;
    const int bid  = blockIdx.x;
    const int qb   = 15 - (bid >> 6);    // longest blocks first
    const int bh   = bid & 63;
    const int h    = bh & 15;
    const int b    = bh >> 4;
    const char* Q  = (const char*)(qr + (long)bh * SS * QKD);
    const char* Kp = (const char*)(kall + (long)bh * SS * QKD);
    const char* Vp = (const char*)(vt + (long)bh * VD * SS);
    char* pw = pbuf[w];

    // hoisted per-lane LDS read offsets (constant across tiles)
    int koff[6], voff[2];
#pragma unroll
    for (int d = 0; d < 6; ++d)
        koff[d] = ql * 384 + (((d * 4 + kg) ^ (ql & 7)) << 4);
#pragma unroll
    for (int t2 = 0; t2 < 2; ++t2)
        voff[t2] = ql * 128 + (((t2 * 4 + kg) ^ (ql & 7)) << 4);
    const int poff = ql * 128;

    // Q fragments (pre-scaled by log2(e)/sqrt(192) at rope time)
    bf16x8 qf[2][6];
#pragma unroll
    for (int m = 0; m < 2; ++m)
#pragma unroll
        for (int d = 0; d < 6; ++d)
            qf[m][d] = *(const bf16x8*)(Q + (long)(qb * 128 + w * 32 + m * 16 + ql) * 384 + d * 64 + kg * 16);

    f32x4 accv[2][8] = {};
    float ms[2] = {-1e30f, -1e30f};
    float ls[2] = {0.f, 0.f};
    const int ntiles = 2 * qb + 2;

    for (int t = 0; t < ntiles; ++t) {
        const int kv0 = t * 64;
        __syncthreads();                 // all waves done reading K/V LDS
        // stage K tile [64][192] (6 x 256 chunks of 16B), source pre-swizzled
#pragma unroll
        for (int i = 0; i < 6; ++i) {
            int idx  = i * 256 + tid;
            int row  = idx / 24;
            int slot = idx - row * 24;
            int ss   = slot ^ (row & 7);
            const char* src = Kp + (long)(kv0 + row) * 384 + ss * 16;
            __builtin_amdgcn_global_load_lds((GV*)src, (LV*)(kbuf + idx * 16), 16, 0, 0);
        }
        // stage V^T tile [128][64]
#pragma unroll
        for (int i = 0; i < 4; ++i) {
            int idx  = i * 256 + tid;
            int row  = idx >> 3;
            int slot = idx & 7;
            int ss   = slot ^ (row & 7);
            const char* src = Vp + (long)row * (SS * 2) + kv0 * 2 + ss * 16;
            __builtin_amdgcn_global_load_lds((GV*)src, (LV*)(vbuf + idx * 16), 16, 0, 0);
        }
        __syncthreads();                 // staged data visible

#pragma unroll
        for (int m = 0; m < 2; ++m) {
            const int qa_min = qb * 128 + w * 32 + m * 16;
            if (kv0 > qa_min + 15) continue;              // fully masked -> skip
            if (kv0 + 63 <= qa_min)
                attn_tile64<false>(kbuf, vbuf, pw, koff, voff, poff, qf[m], accv[m],
                                   ms[m], ls[m], kv0, 0, ql, kg, lane);
            else
                attn_tile64<true>(kbuf, vbuf, pw, koff, voff, poff, qf[m], accv[m],
                                  ms[m], ls[m], kv0, qa_min + ql, ql, kg, lane);
        }
    }
    // ---- epilogue ----
#pragma unroll
    for (int m = 0; m < 2; ++m) {
        float li[4];
#pragma unroll
        for (int r = 0; r < 4; ++r)
            li[r] = 1.0f / __shfl(ls[m], (lane & 48) + kg * 4 + r);
#pragma unroll
        for (int v8 = 0; v8 < 8; ++v8)
#pragma unroll
            for (int r = 0; r < 4; ++r) {
                float o = accv[m][v8][r] * li[r];
                long row = (long)b * SS + qb * 128 + w * 32 + m * 16 + kg * 4 + r;
                ao[row * (long)(HH * VD) + h * VD + v8 * 16 + ql] = (bfu)f2bf(o);
            }
    }
}

// ---------------- workspace layout (bytes) ----------------
#define O_XB   0L                     // x bf16 33,554,432      (later: vt alias)
#define O_WQ   33554432L              // wq bf16 12,582,912
#define O_WA   46137344L              // wkv_a padded 2,621,440
#define O_WB   48758784L              // wkv_b 4,194,304
#define O_WO   52953088L              // wo 8,388,608
#define O_Q1   61341696L              // q proj out 50,331,648  (later: kall alias)
#define O_KV1  111673344L             // kv_a out 10,485,760
#define O_QR   122159104L             // rope'd q 50,331,648
#define O_KVC  172490752L             // kv_c 8,388,608
#define O_KPE  180879360L             // k_pe 1,048,576
#define O_AO   181927936L             // attn out 33,554,432
#define WS_NEED 215482368L
// kvb2 (8192x4096 bf16 = 67,108,864 B) lives in d_out (16,777,216 fp32 = same size)

extern "C" void kernel_launch(void* const* d_in, const int* in_sizes, int n_in,
                              void* d_out, int out_size, void* d_ws, size_t ws_size,
                              hipStream_t stream) {
    const float* x      = (const float*)d_in[0];
    const float* wq     = (const float*)d_in[1];
    const float* wkv_a  = (const float*)d_in[2];
    const float* kvnw   = (const float*)d_in[3];
    const float* wkv_b  = (const float*)d_in[4];
    const float* wo     = (const float*)d_in[5];
    const float* fcos   = (const float*)d_in[6];
    const float* fsin   = (const float*)d_in[7];
    if (ws_size < (size_t)WS_NEED) return;

    char* ws = (char*)d_ws;
    bfu* xb   = (bfu*)(ws + O_XB);
    bfu* wqb  = (bfu*)(ws + O_WQ);
    bfu* wab  = (bfu*)(ws + O_WA);
    bfu* wbb  = (bfu*)(ws + O_WB);
    bfu* wob  = (bfu*)(ws + O_WO);
    bfu* q1   = (bfu*)(ws + O_Q1);
    bfu* kv1  = (bfu*)(ws + O_KV1);
    bfu* qr   = (bfu*)(ws + O_QR);
    bfu* kvc  = (bfu*)(ws + O_KVC);
    bfu* kpe  = (bfu*)(ws + O_KPE);
    bfu* ao   = (bfu*)(ws + O_AO);
    bfu* kall = q1;                   // alias (q1 dead after rope_q)
    bfu* vt   = xb;                   // alias (xb dead after kv_a GEMM)
    bfu* kvb2 = (bfu*)d_out;          // alias (overwritten by final GEMM)

    // 1. casts
    cast_f32_bf16<<<16384, 256, 0, stream>>>(x, xb, 16777216L, 16777216L);
    cast_weights<<<13568, 256, 0, stream>>>(wq, wkv_a, wkv_b, wo, wqb, wab, wbb, wob);

    // 2. projections
    gemm_bt<0><<<dim3(24, 64), 256, 0, stream>>>(xb, wqb, q1, HH * QKD, DD);   // q
    gemm_bt<0><<<dim3(5, 64), 256, 0, stream>>>(xb, wab, kv1, NPAD, DD);       // kv_a

    // 3. rope / rmsnorm
    rope_q<<<49152, 256, 0, stream>>>(q1, qr, fcos, fsin);
    rms_rope_kv<<<ROWS, 256, 0, stream>>>(kv1, kvnw, kvc, kpe, fcos, fsin);

    // 4. kv_b projection (into d_out scratch)
    gemm_bt<0><<<dim3(32, 64), 256, 0, stream>>>(kvc, wbb, kvb2, HH * 256, KVR);

    // 5. K assembly + V transpose
    repack_k<<<12288, 256, 0, stream>>>(kvb2, kpe, kall);
    transpose_v2<<<2048, 256, 0, stream>>>(kvb2, vt);

    // 6. attention (1024 blocks: 64 bh x 16 q-tiles of 128, longest first)
    attn<<<1024, 256, 0, stream>>>(qr, kall, vt, ao);

    // 7. output projection (fp32 out)
    gemm_bt<1><<<dim3(16, 64), 256, 0, stream>>>(ao, wob, d_out, DD, HH * VD);
}

// Round 8
// 592.260 us; speedup vs baseline: 1.6821x; 1.6821x over previous
//
#include <hip/hip_runtime.h>
#include <math.h>

// ---------------- problem constants ----------------
#define BB 4
#define SS 2048
#define DD 2048
#define HH 16
#define NOPE 128
#define ROPE 64
#define VD 128
#define QKD 192         // NOPE+ROPE
#define KVR 512
#define NPAD 640        // KVR+ROPE padded to 128 multiple
#define ROWS (BB*SS)    // 8192
// log2(e) / sqrt(192), folded into Q at rope time
#define SCL2 0.1041216338380858f

typedef __attribute__((ext_vector_type(8))) short bf16x8;
typedef __attribute__((ext_vector_type(4))) float f32x4;
typedef unsigned short bfu;
typedef __attribute__((address_space(1))) const void GV;
typedef __attribute__((address_space(3))) void LV;

__device__ __forceinline__ float bf2f(unsigned int u) {
    unsigned int i = u << 16; float f; __builtin_memcpy(&f, &i, 4); return f;
}
__device__ __forceinline__ unsigned int f2bf(float f) {
    unsigned int i; __builtin_memcpy(&i, &f, 4);
    return (i + 0x7fffu + ((i >> 16) & 1u)) >> 16;
}
__device__ __forceinline__ unsigned int cvt_pk_bf16(float lo, float hi) {
    unsigned int r;
    asm("v_cvt_pk_bf16_f32 %0, %1, %2" : "=v"(r) : "v"(lo), "v"(hi));
    return r;
}

// ---------------- cast fp32 -> bf16 (x input) ----------------
__global__ void cast_f32_bf16(const float* __restrict__ src, bfu* __restrict__ dst,
                              long n_src, long n_dst) {
    long i = (long)blockIdx.x * blockDim.x + threadIdx.x;   // one float4 each
    if (i * 4 >= n_dst) return;
    unsigned int lo = 0, hi = 0;
    if (i * 4 < n_src) {
        float4 v = ((const float4*)src)[i];
        lo = f2bf(v.x) | (f2bf(v.y) << 16);
        hi = f2bf(v.z) | (f2bf(v.w) << 16);
    }
    ((uint2*)dst)[i] = make_uint2(lo, hi);
}

// ---------------- fused weight casts (wq | wkv_a(+pad) | wkv_b | wo) ----------------
__global__ void cast_weights(const float* __restrict__ wq, const float* __restrict__ wa,
                             const float* __restrict__ wb, const float* __restrict__ wo,
                             bfu* __restrict__ dq, bfu* __restrict__ da,
                             bfu* __restrict__ db, bfu* __restrict__ dwo) {
    long i = (long)blockIdx.x * 256 + threadIdx.x;   // one float4 each
    const float* src; bfu* dst; long off, n_src;
    if (i < 1572864L)        { src = wq; dst = dq;  off = i;            n_src = 1572864L; }
    else if (i < 1900544L)   { src = wa; dst = da;  off = i - 1572864L; n_src = 294912L;  }
    else if (i < 2424832L)   { src = wb; dst = db;  off = i - 1900544L; n_src = 524288L;  }
    else if (i < 3473408L)   { src = wo; dst = dwo; off = i - 2424832L; n_src = 1048576L; }
    else return;
    unsigned int lo = 0, hi = 0;
    if (off < n_src) {
        float4 v = ((const float4*)src)[off];
        lo = f2bf(v.x) | (f2bf(v.y) << 16);
        hi = f2bf(v.z) | (f2bf(v.w) << 16);
    }
    ((uint2*)dst)[off] = make_uint2(lo, hi);
}

// ---------------- 128x128 tile bf16 GEMM, C = A[M,K] @ Bt[N,K]^T ----------------
// MODE 0: bf16 out to Cv.  MODE 1: f32 out to Cv.
// MODE 2 (kv_b): split epilogue — col=h*256+wi; wi<128 -> kall (C2), else vpack (Cv).
template <int MODE>
__global__ void __launch_bounds__(256)
gemm_bt(const bfu* __restrict__ A, const bfu* __restrict__ Bt,
        void* __restrict__ Cv, bfu* __restrict__ C2, int N, int K) {
    __shared__ __align__(16) char lds[32768];
    char* AsB = lds;
    char* BsB = lds + 16384;
    const int tid  = threadIdx.x;
    const int lane = tid & 63;
    const int wid  = tid >> 6;
    const int wr   = wid >> 1, wc = wid & 1;
    const long m0 = (long)blockIdx.y * 128;
    const long n0 = (long)blockIdx.x * 128;

    f32x4 acc[4][4] = {};

    const int lr = lane >> 3;            // row within 8-row stripe
    const int SB = (lane & 7) << 4;      // 16B slot within 128B row

    for (int k0 = 0; k0 < K; k0 += 64) {
        __syncthreads();
#pragma unroll
        for (int i = 0; i < 4; ++i) {
            int rb = wid * 32 + i * 8;   // wave-uniform row base
            int R  = rb + lr;
            int c  = (SB ^ ((R & 7) << 4)) >> 1;   // pre-swizzled source column
            const bfu* gA = A  + (m0 + R) * (long)K + k0 + c;
            const bfu* gB = Bt + (n0 + R) * (long)K + k0 + c;
            __builtin_amdgcn_global_load_lds((GV*)gA, (LV*)(AsB + rb * 128), 16, 0, 0);
            __builtin_amdgcn_global_load_lds((GV*)gB, (LV*)(BsB + rb * 128), 16, 0, 0);
        }
        __syncthreads();
#pragma unroll
        for (int kk = 0; kk < 2; ++kk) {
            bf16x8 av[4], bv[4];
            const int cb = kk * 64 + ((lane >> 4) << 4);
#pragma unroll
            for (int m = 0; m < 4; ++m) {
                int R = wr * 64 + m * 16 + (lane & 15);
                av[m] = *(const bf16x8*)(AsB + R * 128 + (cb ^ ((R & 7) << 4)));
            }
#pragma unroll
            for (int n = 0; n < 4; ++n) {
                int R = wc * 64 + n * 16 + (lane & 15);
                bv[n] = *(const bf16x8*)(BsB + R * 128 + (cb ^ ((R & 7) << 4)));
            }
#pragma unroll
            for (int m = 0; m < 4; ++m)
#pragma unroll
                for (int n = 0; n < 4; ++n)
                    acc[m][n] = __builtin_amdgcn_mfma_f32_16x16x32_bf16(av[m], bv[n], acc[m][n], 0, 0, 0);
        }
    }

    const int cr = (lane >> 4) << 2;
    const int cc = lane & 15;
#pragma unroll
    for (int m = 0; m < 4; ++m)
#pragma unroll
        for (int n = 0; n < 4; ++n)
#pragma unroll
            for (int r = 0; r < 4; ++r) {
                long row = m0 + wr * 64 + m * 16 + cr + r;
                long col = n0 + wc * 64 + n * 16 + cc;
                float val = acc[m][n][r];
                if (MODE == 1) {
                    ((float*)Cv)[row * N + col] = val;
                } else if (MODE == 0) {
                    ((bfu*)Cv)[row * N + col] = (bfu)f2bf(val);
                } else {   // MODE 2: kv_b split (N==4096)
                    long b_ = row >> 11;
                    long s  = row & 2047;
                    long h  = col >> 8;
                    long wi = col & 255;
                    if (wi < 128)
                        C2[((b_ * HH + h) * SS + s) * (long)QKD + wi] = (bfu)f2bf(val);
                    else
                        ((bfu*)Cv)[row * 2048 + h * 128 + (wi - 128)] = (bfu)f2bf(val);
                }
            }
}

// ---------------- RoPE on q_pe + rearrange q -> [b][h][s][192], pre-scaled ----------------
__global__ void rope_q(const bfu* __restrict__ q1, bfu* __restrict__ qr,
                       const float* __restrict__ fc, const float* __restrict__ fs) {
    long t = (long)blockIdx.x * 256 + threadIdx.x;   // one (e,o) pair
    const long total = (long)BB * HH * SS * 96;
    if (t >= total) return;
    int  p  = (int)(t % 96);
    long r  = t / 96;
    int  h  = (int)(r % HH);
    long bs = r / HH;                 // b*S + s
    int  s  = (int)(bs % SS);
    long b_ = bs / SS;
    unsigned int v = *(const unsigned int*)(q1 + bs * (HH * QKD) + h * QKD + 2 * p);
    float e = bf2f(v & 0xffff), o = bf2f(v >> 16);
    if (p >= 64) {
        int i = p - 64;
        float c = fc[s * 32 + i], sn = fs[s * 32 + i];
        float ye = e * c - o * sn;
        float yo = e * sn + o * c;
        e = ye; o = yo;
    }
    e *= SCL2; o *= SCL2;             // fold softmax scale + log2(e) into Q
    unsigned int out = f2bf(e) | (f2bf(o) << 16);
    *(unsigned int*)(qr + ((b_ * HH + h) * SS + s) * (long)QKD + 2 * p) = out;
}

// ---------------- RMSNorm(kv_c) + RoPE(k_pe), one block per (b,s) row ----------------
__global__ void __launch_bounds__(256)
rms_rope_kv(const bfu* __restrict__ kv1, const float* __restrict__ wn,
            bfu* __restrict__ kvc, bfu* __restrict__ kpe,
            const float* __restrict__ fc, const float* __restrict__ fs) {
    const int row = blockIdx.x;            // b*S + s
    const int t   = threadIdx.x;
    const int s   = row & (SS - 1);
    const long base = (long)row * NPAD;
    unsigned int v = *(const unsigned int*)(kv1 + base + 2 * t);
    float a = bf2f(v & 0xffff), c2 = bf2f(v >> 16);
    float ssum = a * a + c2 * c2;
#pragma unroll
    for (int d = 1; d < 64; d <<= 1) ssum += __shfl_xor(ssum, d);
    __shared__ float red[4];
    const int lane = t & 63, w = t >> 6;
    if (lane == 0) red[w] = ssum;
    __syncthreads();
    float tot = red[0] + red[1] + red[2] + red[3];
    float scale = rsqrtf(tot * (1.0f / 512.0f) + 1e-6f);
    float w0 = wn[2 * t], w1 = wn[2 * t + 1];
    unsigned int out = f2bf(a * scale * w0) | (f2bf(c2 * scale * w1) << 16);
    *(unsigned int*)(kvc + (long)row * KVR + 2 * t) = out;
    if (t < 32) {
        unsigned int pv = *(const unsigned int*)(kv1 + base + KVR + 2 * t);
        float e = bf2f(pv & 0xffff), o = bf2f(pv >> 16);
        float cc = fc[s * 32 + t], sn = fs[s * 32 + t];
        unsigned int po = f2bf(e * cc - o * sn) | (f2bf(e * sn + o * cc) << 16);
        *(unsigned int*)(kpe + (long)row * ROPE + 2 * t) = po;
    }
}

// ---------------- k_pe fill: kall[b][h][s][128..191] = kpe[b][s][:] ----------------
__global__ void pe_fill(const bfu* __restrict__ kpe, bfu* __restrict__ kall) {
    long t = (long)blockIdx.x * 256 + threadIdx.x;   // one 8-elem chunk
    int  ch = (int)(t & 7);
    long r  = t >> 3;
    int  s  = (int)(r & 2047);
    long bh = r >> 11;                 // 0..63
    long b_ = bh >> 4;
    bf16x8 v = *(const bf16x8*)(kpe + (b_ * SS + s) * (long)ROPE + ch * 8);
    *(bf16x8*)(kall + (bh * SS + s) * (long)QKD + NOPE + ch * 8) = v;
}

// ---------------- V transpose via LDS tile: vt[b][h][v][s] (reads vpack) ----------------
__global__ void __launch_bounds__(256)
transpose_v2(const bfu* __restrict__ vpack, bfu* __restrict__ vt) {
    __shared__ __align__(16) char tile[64 * 256];   // 16 KB
    const int tid = threadIdx.x;
    const int bid = blockIdx.x;          // 64 bh * 32 s-tiles
    const int st  = bid & 31;
    const int bh  = bid >> 5;
    const int h   = bh & 15;
    const long b_ = bh >> 4;
    const long sbase = b_ * SS + st * 64;
#pragma unroll
    for (int i = 0; i < 4; ++i) {
        int idx = i * 256 + tid;
        int row = idx >> 4;
        int ch  = (idx & 15) ^ ((row >> 3) & 7);
        const bfu* src = vpack + (sbase + row) * 2048 + h * 128 + ch * 8;
        __builtin_amdgcn_global_load_lds((GV*)src, (LV*)(tile + idx * 16), 16, 0, 0);
    }
    __syncthreads();
#pragma unroll
    for (int i = 0; i < 4; ++i) {
        int idx = i * 256 + tid;
        int sc = idx & 7;            // s-chunk of 8
        int v  = (idx >> 3) & 127;
        bfu tmp[8];
#pragma unroll
        for (int k = 0; k < 8; ++k) {
            int row = sc * 8 + k;
            tmp[k] = *(const bfu*)(tile + row * 256 + (((v >> 3) ^ ((row >> 3) & 7)) << 4) + (v & 7) * 2);
        }
        *(bf16x8*)(vt + ((long)bh * VD + v) * SS + st * 64 + sc * 8) = *(bf16x8*)tmp;
    }
}

// ---------------- flash causal attention v8 (R2 structure + op-level diet) ----------------
// 4 waves x 32 q-rows, KV tile 64 LDS-staged from compact kall/vt (L3-resident).
// Diet: pre-scaled Q (exp2 domain), cvt_pk P-pack, defer-max, reciprocal epilogue.
__device__ __forceinline__ void attn_tile64(
    const char* kbuf, const char* vbuf, char* pw,
    const bf16x8 (&qf)[6], f32x4 (&accv)[8],
    float& ms, float& ls, int kv0, int qa, int ql, int kg, int lane) {
    // ---- QK^T from LDS: C[kv][q] ----
    f32x4 sc[4] = {};
#pragma unroll
    for (int j = 0; j < 4; ++j)
#pragma unroll
        for (int d = 0; d < 6; ++d) {
            int row  = j * 16 + ql;
            int slot = (d * 4 + kg) ^ (ql & 7);
            bf16x8 kf = *(const bf16x8*)(kbuf + row * 384 + slot * 16);
            sc[j] = __builtin_amdgcn_mfma_f32_16x16x32_bf16(kf, qf[d], sc[j], 0, 0, 0);
        }
    // ---- online softmax (q = ql lane-local column; Q pre-scaled, exp2 domain) ----
    float p[4][4];
    float mx = -1e30f;
#pragma unroll
    for (int j = 0; j < 4; ++j)
#pragma unroll
        for (int r = 0; r < 4; ++r) {
            float s = sc[j][r];
            int kv = kv0 + j * 16 + kg * 4 + r;
            s = (kv > qa) ? -1e30f : s;
            p[j][r] = s;
            mx = fmaxf(mx, s);
        }
    mx = fmaxf(mx, __shfl_xor(mx, 16));
    mx = fmaxf(mx, __shfl_xor(mx, 32));
    float rs = 0.f;
    if (__all(mx <= ms)) {            // defer-max: running max unchanged, no rescale
#pragma unroll
        for (int j = 0; j < 4; ++j)
#pragma unroll
            for (int r = 0; r < 4; ++r) {
                float e = exp2f(p[j][r] - ms);
                p[j][r] = e;
                rs += e;
            }
        rs += __shfl_xor(rs, 16);
        rs += __shfl_xor(rs, 32);
        ls += rs;
    } else {
        float mn = fmaxf(ms, mx);
        float al = exp2f(ms - mn);
        ms = mn;
#pragma unroll
        for (int j = 0; j < 4; ++j)
#pragma unroll
            for (int r = 0; r < 4; ++r) {
                float e = exp2f(p[j][r] - mn);
                p[j][r] = e;
                rs += e;
            }
        rs += __shfl_xor(rs, 16);
        rs += __shfl_xor(rs, 32);
        ls = ls * al + rs;
        float alT[4];
#pragma unroll
        for (int r = 0; r < 4; ++r)
            alT[r] = __shfl(al, (lane & 48) + kg * 4 + r);
#pragma unroll
        for (int v8 = 0; v8 < 8; ++v8)
#pragma unroll
            for (int r = 0; r < 4; ++r)
                accv[v8][r] *= alT[r];
    }
    // ---- repack P -> wave LDS [16 q][64 kv], swizzled; cvt_pk packing ----
#pragma unroll
    for (int j = 0; j < 4; ++j) {
        uint2 u;
        u.x = cvt_pk_bf16(p[j][0], p[j][1]);
        u.y = cvt_pk_bf16(p[j][2], p[j][3]);
        int slot = (2 * j + (kg >> 1)) ^ (ql & 7);
        *(uint2*)(pw + ql * 128 + slot * 16 + (kg & 1) * 8) = u;
    }
    asm volatile("s_waitcnt lgkmcnt(0)" ::: "memory");
    // ---- PV from LDS: out[q][v] += P V ----
#pragma unroll
    for (int t2 = 0; t2 < 2; ++t2) {
        int ps = (t2 * 4 + kg) ^ (ql & 7);
        bf16x8 pa = *(const bf16x8*)(pw + ql * 128 + ps * 16);
#pragma unroll
        for (int v8 = 0; v8 < 8; ++v8) {
            int vrow = v8 * 16 + ql;
            int vs   = (t2 * 4 + kg) ^ (ql & 7);
            bf16x8 vf = *(const bf16x8*)(vbuf + vrow * 128 + vs * 16);
            accv[v8] = __builtin_amdgcn_mfma_f32_16x16x32_bf16(pa, vf, accv[v8], 0, 0, 0);
        }
    }
}

__global__ void __launch_bounds__(256)
attn(const bfu* __restrict__ qr, const bfu* __restrict__ kall,
     const bfu* __restrict__ vt, bfu* __restrict__ ao) {
    __shared__ __align__(16) char kbuf[64 * 384];    // 24576
    __shared__ __align__(16) char vbuf[128 * 128];   // 16384
    __shared__ __align__(16) char pbuf[4][2048];     //  8192
    const int tid  = threadIdx.x;
    const int lane = tid & 63;
    const int w    = tid >> 6;
    const int ql   = lane & 15;
    const int kg   = lane >> 4;
    const int bid  = blockIdx.x;
    const int qb   = 15 - (bid >> 6);    // longest blocks first
    const int bh   = bid & 63;
    const int h    = bh & 15;
    const int b    = bh >> 4;
    const char* Q  = (const char*)(qr + (long)bh * SS * QKD);
    const char* Kp = (const char*)(kall + (long)bh * SS * QKD);
    const char* Vp = (const char*)(vt + (long)bh * VD * SS);
    char* pw = pbuf[w];

    // Q fragments (pre-scaled by log2(e)/sqrt(192) at rope time)
    bf16x8 qf[2][6];
#pragma unroll
    for (int m = 0; m < 2; ++m)
#pragma unroll
        for (int d = 0; d < 6; ++d)
            qf[m][d] = *(const bf16x8*)(Q + (long)(qb * 128 + w * 32 + m * 16 + ql) * 384 + d * 64 + kg * 16);

    f32x4 accv[2][8] = {};
    float ms[2] = {-1e30f, -1e30f};
    float ls[2] = {0.f, 0.f};
    const int ntiles = 2 * qb + 2;

    for (int t = 0; t < ntiles; ++t) {
        const int kv0 = t * 64;
        __syncthreads();                 // all waves done reading K/V LDS
        // stage K tile [64][192] (6 x 256 chunks of 16B), source pre-swizzled
#pragma unroll
        for (int i = 0; i < 6; ++i) {
            int idx  = i * 256 + tid;
            int row  = idx / 24;
            int slot = idx - row * 24;
            int ss   = slot ^ (row & 7);
            const char* src = Kp + (long)(kv0 + row) * 384 + ss * 16;
            __builtin_amdgcn_global_load_lds((GV*)src, (LV*)(kbuf + idx * 16), 16, 0, 0);
        }
        // stage V^T tile [128][64]
#pragma unroll
        for (int i = 0; i < 4; ++i) {
            int idx  = i * 256 + tid;
            int row  = idx >> 3;
            int slot = idx & 7;
            int ss   = slot ^ (row & 7);
            const char* src = Vp + (long)row * (SS * 2) + kv0 * 2 + ss * 16;
            __builtin_amdgcn_global_load_lds((GV*)src, (LV*)(vbuf + idx * 16), 16, 0, 0);
        }
        __syncthreads();                 // staged data visible

#pragma unroll
        for (int m = 0; m < 2; ++m) {
            const int qa = qb * 128 + w * 32 + m * 16 + ql;
            attn_tile64(kbuf, vbuf, pw, qf[m], accv[m], ms[m], ls[m],
                        kv0, qa, ql, kg, lane);
        }
    }
    // ---- epilogue ----
#pragma unroll
    for (int m = 0; m < 2; ++m) {
        float li[4];
#pragma unroll
        for (int r = 0; r < 4; ++r)
            li[r] = 1.0f / __shfl(ls[m], (lane & 48) + kg * 4 + r);
#pragma unroll
        for (int v8 = 0; v8 < 8; ++v8)
#pragma unroll
            for (int r = 0; r < 4; ++r) {
                float o = accv[m][v8][r] * li[r];
                long row = (long)b * SS + qb * 128 + w * 32 + m * 16 + kg * 4 + r;
                ao[row * (long)(HH * VD) + h * VD + v8 * 16 + ql] = (bfu)f2bf(o);
            }
    }
}

// ---------------- workspace layout (bytes) ----------------
#define O_XB   0L                     // x bf16 33,554,432      (later: vt alias)
#define O_WQ   33554432L              // wq bf16 12,582,912
#define O_WA   46137344L              // wkv_a padded 2,621,440
#define O_WB   48758784L              // wkv_b 4,194,304
#define O_WO   52953088L              // wo 8,388,608
#define O_Q1   61341696L              // q proj out 50,331,648  (later: kall alias)
#define O_KV1  111673344L             // kv_a out 10,485,760
#define O_QR   122159104L             // rope'd q 50,331,648
#define O_KVC  172490752L             // kv_c 8,388,608
#define O_KPE  180879360L             // k_pe 1,048,576
#define O_AO   181927936L             // attn out 33,554,432
#define WS_NEED 215482368L
// vpack (8192x2048 bf16 = 33,554,432 B) lives in d_out (67,108,864 B)

extern "C" void kernel_launch(void* const* d_in, const int* in_sizes, int n_in,
                              void* d_out, int out_size, void* d_ws, size_t ws_size,
                              hipStream_t stream) {
    const float* x      = (const float*)d_in[0];
    const float* wq     = (const float*)d_in[1];
    const float* wkv_a  = (const float*)d_in[2];
    const float* kvnw   = (const float*)d_in[3];
    const float* wkv_b  = (const float*)d_in[4];
    const float* wo     = (const float*)d_in[5];
    const float* fcos   = (const float*)d_in[6];
    const float* fsin   = (const float*)d_in[7];
    if (ws_size < (size_t)WS_NEED) return;

    char* ws = (char*)d_ws;
    bfu* xb   = (bfu*)(ws + O_XB);
    bfu* wqb  = (bfu*)(ws + O_WQ);
    bfu* wab  = (bfu*)(ws + O_WA);
    bfu* wbb  = (bfu*)(ws + O_WB);
    bfu* wob  = (bfu*)(ws + O_WO);
    bfu* q1   = (bfu*)(ws + O_Q1);
    bfu* kv1  = (bfu*)(ws + O_KV1);
    bfu* qr   = (bfu*)(ws + O_QR);
    bfu* kvc  = (bfu*)(ws + O_KVC);
    bfu* kpe  = (bfu*)(ws + O_KPE);
    bfu* ao   = (bfu*)(ws + O_AO);
    bfu* kall = q1;                   // alias (q1 dead after rope_q)
    bfu* vt   = xb;                   // alias (xb dead after kv_a GEMM)
    bfu* vpack = (bfu*)d_out;         // alias (consumed before final GEMM)

    // 1. casts
    cast_f32_bf16<<<16384, 256, 0, stream>>>(x, xb, 16777216L, 16777216L);
    cast_weights<<<13568, 256, 0, stream>>>(wq, wkv_a, wkv_b, wo, wqb, wab, wbb, wob);

    // 2. projections
    gemm_bt<0><<<dim3(24, 64), 256, 0, stream>>>(xb, wqb, q1, nullptr, HH * QKD, DD);  // q
    gemm_bt<0><<<dim3(5, 64), 256, 0, stream>>>(xb, wab, kv1, nullptr, NPAD, DD);      // kv_a

    // 3. rope / rmsnorm
    rope_q<<<49152, 256, 0, stream>>>(q1, qr, fcos, fsin);
    rms_rope_kv<<<ROWS, 256, 0, stream>>>(kv1, kvnw, kvc, kpe, fcos, fsin);

    // 4. kv_b projection: nope -> kall (direct), v -> vpack (d_out scratch)
    gemm_bt<2><<<dim3(32, 64), 256, 0, stream>>>(kvc, wbb, vpack, kall, HH * 256, KVR);

    // 5. k_pe fill + V transpose
    pe_fill<<<4096, 256, 0, stream>>>(kpe, kall);
    transpose_v2<<<2048, 256, 0, stream>>>(vpack, vt);

    // 6. attention (1024 blocks: 64 bh x 16 q-tiles of 128, longest first)
    attn<<<1024, 256, 0, stream>>>(qr, kall, vt, ao);

    // 7. output projection (fp32 out)
    gemm_bt<1><<<dim3(16, 64), 256, 0, stream>>>(ao, wob, d_out, nullptr, DD, HH * VD);
}

// Round 9
// 524.833 us; speedup vs baseline: 1.8982x; 1.1285x over previous
//
#include <hip/hip_runtime.h>
#include <math.h>

// ---------------- problem constants ----------------
#define BB 4
#define SS 2048
#define DD 2048
#define HH 16
#define NOPE 128
#define ROPE 64
#define VD 128
#define QKD 192         // NOPE+ROPE
#define KVR 512
#define NP1 3712        // merged proj1 width: 3072 (q) + 640 (kv_a padded)
#define ROWS (BB*SS)    // 8192
// log2(e) / sqrt(192), folded into wq at cast time
#define SCL2 0.1041216338380858f

typedef __attribute__((ext_vector_type(8))) short bf16x8;
typedef __attribute__((ext_vector_type(4))) float f32x4;
typedef unsigned short bfu;
typedef __attribute__((address_space(1))) const void GV;
typedef __attribute__((address_space(3))) void LV;

__device__ __forceinline__ float bf2f(unsigned int u) {
    unsigned int i = u << 16; float f; __builtin_memcpy(&f, &i, 4); return f;
}
__device__ __forceinline__ unsigned int f2bf(float f) {
    unsigned int i; __builtin_memcpy(&i, &f, 4);
    return (i + 0x7fffu + ((i >> 16) & 1u)) >> 16;
}
__device__ __forceinline__ unsigned int cvt_pk_bf16(float lo, float hi) {
    unsigned int r;
    asm("v_cvt_pk_bf16_f32 %0, %1, %2" : "=v"(r) : "v"(lo), "v"(hi));
    return r;
}

// ---------------- cast fp32 -> bf16 (x input) ----------------
__global__ void cast_f32_bf16(const float* __restrict__ src, bfu* __restrict__ dst,
                              long n_src, long n_dst) {
    long i = (long)blockIdx.x * blockDim.x + threadIdx.x;   // one float4 each
    if (i * 4 >= n_dst) return;
    unsigned int lo = 0, hi = 0;
    if (i * 4 < n_src) {
        float4 v = ((const float4*)src)[i];
        lo = f2bf(v.x) | (f2bf(v.y) << 16);
        hi = f2bf(v.z) | (f2bf(v.w) << 16);
    }
    ((uint2*)dst)[i] = make_uint2(lo, hi);
}

// ---------------- fused weight casts (wq*SCL2 | wkv_a(+pad) | wkv_b | wo) ----------------
__global__ void cast_weights(const float* __restrict__ wq, const float* __restrict__ wa,
                             const float* __restrict__ wb, const float* __restrict__ wo,
                             bfu* __restrict__ dq, bfu* __restrict__ da,
                             bfu* __restrict__ db, bfu* __restrict__ dwo) {
    long i = (long)blockIdx.x * 256 + threadIdx.x;   // one float4 each
    const float* src; bfu* dst; long off, n_src; float scl = 1.0f;
    if (i < 1572864L)        { src = wq; dst = dq;  off = i;            n_src = 1572864L; scl = SCL2; }
    else if (i < 1900544L)   { src = wa; dst = da;  off = i - 1572864L; n_src = 294912L;  }
    else if (i < 2424832L)   { src = wb; dst = db;  off = i - 1900544L; n_src = 524288L;  }
    else if (i < 3473408L)   { src = wo; dst = dwo; off = i - 2424832L; n_src = 1048576L; }
    else return;
    unsigned int lo = 0, hi = 0;
    if (off < n_src) {
        float4 v = ((const float4*)src)[off];
        lo = f2bf(v.x * scl) | (f2bf(v.y * scl) << 16);
        hi = f2bf(v.z * scl) | (f2bf(v.w * scl) << 16);
    }
    ((uint2*)dst)[off] = make_uint2(lo, hi);
}

// ---------------- 128x128 tile bf16 GEMM, C = A[M,K] @ Bt[N,K]^T ----------------
// MODE 0: bf16 out to Cv.  MODE 1: f32 out to Cv.
// MODE 2 (kv_b): split epilogue — col=h*256+wi; wi<128 -> kall (C2), else vpack (Cv).
template <int MODE>
__global__ void __launch_bounds__(256)
gemm_bt(const bfu* __restrict__ A, const bfu* __restrict__ Bt,
        void* __restrict__ Cv, bfu* __restrict__ C2, int N, int K) {
    __shared__ __align__(16) char lds[32768];
    char* AsB = lds;
    char* BsB = lds + 16384;
    const int tid  = threadIdx.x;
    const int lane = tid & 63;
    const int wid  = tid >> 6;
    const int wr   = wid >> 1, wc = wid & 1;
    const long m0 = (long)blockIdx.y * 128;
    const long n0 = (long)blockIdx.x * 128;

    f32x4 acc[4][4] = {};

    const int lr = lane >> 3;            // row within 8-row stripe
    const int SB = (lane & 7) << 4;      // 16B slot within 128B row

    for (int k0 = 0; k0 < K; k0 += 64) {
        __syncthreads();
#pragma unroll
        for (int i = 0; i < 4; ++i) {
            int rb = wid * 32 + i * 8;   // wave-uniform row base
            int R  = rb + lr;
            int c  = (SB ^ ((R & 7) << 4)) >> 1;   // pre-swizzled source column
            const bfu* gA = A  + (m0 + R) * (long)K + k0 + c;
            const bfu* gB = Bt + (n0 + R) * (long)K + k0 + c;
            __builtin_amdgcn_global_load_lds((GV*)gA, (LV*)(AsB + rb * 128), 16, 0, 0);
            __builtin_amdgcn_global_load_lds((GV*)gB, (LV*)(BsB + rb * 128), 16, 0, 0);
        }
        __syncthreads();
#pragma unroll
        for (int kk = 0; kk < 2; ++kk) {
            bf16x8 av[4], bv[4];
            const int cb = kk * 64 + ((lane >> 4) << 4);
#pragma unroll
            for (int m = 0; m < 4; ++m) {
                int R = wr * 64 + m * 16 + (lane & 15);
                av[m] = *(const bf16x8*)(AsB + R * 128 + (cb ^ ((R & 7) << 4)));
            }
#pragma unroll
            for (int n = 0; n < 4; ++n) {
                int R = wc * 64 + n * 16 + (lane & 15);
                bv[n] = *(const bf16x8*)(BsB + R * 128 + (cb ^ ((R & 7) << 4)));
            }
#pragma unroll
            for (int m = 0; m < 4; ++m)
#pragma unroll
                for (int n = 0; n < 4; ++n)
                    acc[m][n] = __builtin_amdgcn_mfma_f32_16x16x32_bf16(av[m], bv[n], acc[m][n], 0, 0, 0);
        }
    }

    const int cr = (lane >> 4) << 2;
    const int cc = lane & 15;
#pragma unroll
    for (int m = 0; m < 4; ++m)
#pragma unroll
        for (int n = 0; n < 4; ++n)
#pragma unroll
            for (int r = 0; r < 4; ++r) {
                long row = m0 + wr * 64 + m * 16 + cr + r;
                long col = n0 + wc * 64 + n * 16 + cc;
                float val = acc[m][n][r];
                if (MODE == 1) {
                    ((float*)Cv)[row * N + col] = val;
                } else if (MODE == 0) {
                    ((bfu*)Cv)[row * N + col] = (bfu)f2bf(val);
                } else {   // MODE 2: kv_b split (N==4096)
                    long b_ = row >> 11;
                    long s  = row & 2047;
                    long h  = col >> 8;
                    long wi = col & 255;
                    if (wi < 128)
                        C2[((b_ * HH + h) * SS + s) * (long)QKD + wi] = (bfu)f2bf(val);
                    else
                        ((bfu*)Cv)[row * 2048 + h * 128 + (wi - 128)] = (bfu)f2bf(val);
                }
            }
}

// ---------------- RoPE on q_pe + rearrange q -> [b][h][s][192] ----------------
// Q already scaled by SCL2 via wq cast. One 16B chunk (8 bf16) per thread.
__global__ void rope_q(const bfu* __restrict__ p1, bfu* __restrict__ qr,
                       const float* __restrict__ fc, const float* __restrict__ fs) {
    long t = (long)blockIdx.x * 256 + threadIdx.x;   // one bf16x8 chunk
    int  ch = (int)(t % 24);
    long r  = t / 24;
    int  s  = (int)(r & 2047);
    long bh = r >> 11;                 // 0..63
    long b_ = bh >> 4;
    int  h  = (int)(bh & 15);
    const bfu* src = p1 + (b_ * SS + s) * (long)NP1 + h * QKD + ch * 8;
    bfu* dst = qr + (bh * SS + s) * (long)QKD + ch * 8;
    bf16x8 v = *(const bf16x8*)src;
    if (ch >= 16) {
        int i0 = (ch - 16) * 4;        // 4 rope pairs
        unsigned int out[4];
#pragma unroll
        for (int k = 0; k < 4; ++k) {
            float e = bf2f((unsigned short)v[2 * k]);
            float o = bf2f((unsigned short)v[2 * k + 1]);
            float c = fc[s * 32 + i0 + k], sn = fs[s * 32 + i0 + k];
            out[k] = cvt_pk_bf16(e * c - o * sn, e * sn + o * c);
        }
        uint4 u = make_uint4(out[0], out[1], out[2], out[3]);
        *(uint4*)dst = u;
    } else {
        *(bf16x8*)dst = v;
    }
}

// ---------------- RMSNorm(kv_c) + RoPE(k_pe), one block per (b,s) row ----------------
__global__ void __launch_bounds__(256)
rms_rope_kv(const bfu* __restrict__ p1, const float* __restrict__ wn,
            bfu* __restrict__ kvc, bfu* __restrict__ kpe,
            const float* __restrict__ fc, const float* __restrict__ fs) {
    const int row = blockIdx.x;            // b*S + s
    const int t   = threadIdx.x;
    const int s   = row & (SS - 1);
    const long base = (long)row * NP1 + 3072;
    unsigned int v = *(const unsigned int*)(p1 + base + 2 * t);
    float a = bf2f(v & 0xffff), c2 = bf2f(v >> 16);
    float ssum = a * a + c2 * c2;
#pragma unroll
    for (int d = 1; d < 64; d <<= 1) ssum += __shfl_xor(ssum, d);
    __shared__ float red[4];
    const int lane = t & 63, w = t >> 6;
    if (lane == 0) red[w] = ssum;
    __syncthreads();
    float tot = red[0] + red[1] + red[2] + red[3];
    float scale = rsqrtf(tot * (1.0f / 512.0f) + 1e-6f);
    float w0 = wn[2 * t], w1 = wn[2 * t + 1];
    unsigned int out = f2bf(a * scale * w0) | (f2bf(c2 * scale * w1) << 16);
    *(unsigned int*)(kvc + (long)row * KVR + 2 * t) = out;
    if (t < 32) {
        unsigned int pv = *(const unsigned int*)(p1 + base + KVR + 2 * t);
        float e = bf2f(pv & 0xffff), o = bf2f(pv >> 16);
        float cc = fc[s * 32 + t], sn = fs[s * 32 + t];
        unsigned int po = f2bf(e * cc - o * sn) | (f2bf(e * sn + o * cc) << 16);
        *(unsigned int*)(kpe + (long)row * ROPE + 2 * t) = po;
    }
}

// ---------------- k_pe fill: kall[b][h][s][128..191] = kpe[b][s][:] ----------------
__global__ void pe_fill(const bfu* __restrict__ kpe, bfu* __restrict__ kall) {
    long t = (long)blockIdx.x * 256 + threadIdx.x;   // one 8-elem chunk
    int  ch = (int)(t & 7);
    long r  = t >> 3;
    int  s  = (int)(r & 2047);
    long bh = r >> 11;                 // 0..63
    long b_ = bh >> 4;
    bf16x8 v = *(const bf16x8*)(kpe + (b_ * SS + s) * (long)ROPE + ch * 8);
    *(bf16x8*)(kall + (bh * SS + s) * (long)QKD + NOPE + ch * 8) = v;
}

// ---------------- V transpose via LDS tile: vt[b][h][v][s] (reads vpack) ----------------
__global__ void __launch_bounds__(256)
transpose_v2(const bfu* __restrict__ vpack, bfu* __restrict__ vt) {
    __shared__ __align__(16) char tile[64 * 256];   // 16 KB
    const int tid = threadIdx.x;
    const int bid = blockIdx.x;          // 64 bh * 32 s-tiles
    const int st  = bid & 31;
    const int bh  = bid >> 5;
    const int h   = bh & 15;
    const long b_ = bh >> 4;
    const long sbase = b_ * SS + st * 64;
#pragma unroll
    for (int i = 0; i < 4; ++i) {
        int idx = i * 256 + tid;
        int row = idx >> 4;
        int ch  = (idx & 15) ^ ((row >> 3) & 7);
        const bfu* src = vpack + (sbase + row) * 2048 + h * 128 + ch * 8;
        __builtin_amdgcn_global_load_lds((GV*)src, (LV*)(tile + idx * 16), 16, 0, 0);
    }
    __syncthreads();
#pragma unroll
    for (int i = 0; i < 4; ++i) {
        int idx = i * 256 + tid;
        int sc = idx & 7;            // s-chunk of 8
        int v  = (idx >> 3) & 127;
        bfu tmp[8];
#pragma unroll
        for (int k = 0; k < 8; ++k) {
            int row = sc * 8 + k;
            tmp[k] = *(const bfu*)(tile + row * 256 + (((v >> 3) ^ ((row >> 3) & 7)) << 4) + (v & 7) * 2);
        }
        *(bf16x8*)(vt + ((long)bh * VD + v) * SS + st * 64 + sc * 8) = *(bf16x8*)tmp;
    }
}

// ---------------- flash causal attention v9 (8 waves x 16 q-rows) ----------------
// Same K/V LDS memory structure as R8 (proven); finer wave granularity: each of
// 8 waves owns 16 q-rows -> half the live VGPR state, 2x independent waves to
// overlap softmax VALU with other waves' MFMA.
__device__ __forceinline__ void attn_tile64(
    const char* kbuf, const char* vbuf, char* pw,
    const bf16x8 (&qf)[6], f32x4 (&accv)[8],
    float& ms, float& ls, int kv0, int qa, int ql, int kg, int lane) {
    // ---- QK^T from LDS: C[kv][q] ----
    f32x4 sc[4] = {};
#pragma unroll
    for (int j = 0; j < 4; ++j)
#pragma unroll
        for (int d = 0; d < 6; ++d) {
            int row  = j * 16 + ql;
            int slot = (d * 4 + kg) ^ (ql & 7);
            bf16x8 kf = *(const bf16x8*)(kbuf + row * 384 + slot * 16);
            sc[j] = __builtin_amdgcn_mfma_f32_16x16x32_bf16(kf, qf[d], sc[j], 0, 0, 0);
        }
    // ---- online softmax (q = ql lane-local column; Q pre-scaled, exp2 domain) ----
    float p[4][4];
    float mx = -1e30f;
#pragma unroll
    for (int j = 0; j < 4; ++j)
#pragma unroll
        for (int r = 0; r < 4; ++r) {
            float s = sc[j][r];
            int kv = kv0 + j * 16 + kg * 4 + r;
            s = (kv > qa) ? -1e30f : s;
            p[j][r] = s;
            mx = fmaxf(mx, s);
        }
    mx = fmaxf(mx, __shfl_xor(mx, 16));
    mx = fmaxf(mx, __shfl_xor(mx, 32));
    float rs = 0.f;
    if (__all(mx <= ms)) {            // defer-max: running max unchanged, no rescale
#pragma unroll
        for (int j = 0; j < 4; ++j)
#pragma unroll
            for (int r = 0; r < 4; ++r) {
                float e = exp2f(p[j][r] - ms);
                p[j][r] = e;
                rs += e;
            }
        rs += __shfl_xor(rs, 16);
        rs += __shfl_xor(rs, 32);
        ls += rs;
    } else {
        float mn = fmaxf(ms, mx);
        float al = exp2f(ms - mn);
        ms = mn;
#pragma unroll
        for (int j = 0; j < 4; ++j)
#pragma unroll
            for (int r = 0; r < 4; ++r) {
                float e = exp2f(p[j][r] - mn);
                p[j][r] = e;
                rs += e;
            }
        rs += __shfl_xor(rs, 16);
        rs += __shfl_xor(rs, 32);
        ls = ls * al + rs;
        float alT[4];
#pragma unroll
        for (int r = 0; r < 4; ++r)
            alT[r] = __shfl(al, (lane & 48) + kg * 4 + r);
#pragma unroll
        for (int v8 = 0; v8 < 8; ++v8)
#pragma unroll
            for (int r = 0; r < 4; ++r)
                accv[v8][r] *= alT[r];
    }
    // ---- repack P -> wave LDS [16 q][64 kv], swizzled; cvt_pk packing ----
#pragma unroll
    for (int j = 0; j < 4; ++j) {
        uint2 u;
        u.x = cvt_pk_bf16(p[j][0], p[j][1]);
        u.y = cvt_pk_bf16(p[j][2], p[j][3]);
        int slot = (2 * j + (kg >> 1)) ^ (ql & 7);
        *(uint2*)(pw + ql * 128 + slot * 16 + (kg & 1) * 8) = u;
    }
    asm volatile("s_waitcnt lgkmcnt(0)" ::: "memory");
    // ---- PV from LDS: out[q][v] += P V ----
#pragma unroll
    for (int t2 = 0; t2 < 2; ++t2) {
        int ps = (t2 * 4 + kg) ^ (ql & 7);
        bf16x8 pa = *(const bf16x8*)(pw + ql * 128 + ps * 16);
#pragma unroll
        for (int v8 = 0; v8 < 8; ++v8) {
            int vrow = v8 * 16 + ql;
            int vs   = (t2 * 4 + kg) ^ (ql & 7);
            bf16x8 vf = *(const bf16x8*)(vbuf + vrow * 128 + vs * 16);
            accv[v8] = __builtin_amdgcn_mfma_f32_16x16x32_bf16(pa, vf, accv[v8], 0, 0, 0);
        }
    }
}

__global__ void __launch_bounds__(512)
attn(const bfu* __restrict__ qr, const bfu* __restrict__ kall,
     const bfu* __restrict__ vt, bfu* __restrict__ ao) {
    __shared__ __align__(16) char kbuf[64 * 384];    // 24576
    __shared__ __align__(16) char vbuf[128 * 128];   // 16384
    __shared__ __align__(16) char pbuf[8][2048];     // 16384  -> 57344 total
    const int tid  = threadIdx.x;
    const int lane = tid & 63;
    const int w    = tid >> 6;           // 0..7
    const int ql   = lane & 15;
    const int kg   = lane >> 4;
    const int bid  = blockIdx.x;
    const int qb   = 15 - (bid >> 6);    // longest blocks first
    const int bh   = bid & 63;
    const int h    = bh & 15;
    const int b    = bh >> 4;
    const char* Q  = (const char*)(qr + (long)bh * SS * QKD);
    const char* Kp = (const char*)(kall + (long)bh * SS * QKD);
    const char* Vp = (const char*)(vt + (long)bh * VD * SS);
    char* pw = pbuf[w];

    const int qa_min = qb * 128 + w * 16;
    const int qa = qa_min + ql;

    // Q fragments (pre-scaled by log2(e)/sqrt(192) via wq cast)
    bf16x8 qf[6];
#pragma unroll
    for (int d = 0; d < 6; ++d)
        qf[d] = *(const bf16x8*)(Q + (long)(qa_min + ql) * 384 + d * 64 + kg * 16);

    f32x4 accv[8] = {};
    float ms = -1e30f, ls = 0.f;
    const int ntiles = 2 * qb + 2;

    for (int t = 0; t < ntiles; ++t) {
        const int kv0 = t * 64;
        __syncthreads();                 // all waves done reading K/V LDS
        // stage K tile [64][192] (1536 x 16B chunks over 512 threads)
#pragma unroll
        for (int i = 0; i < 3; ++i) {
            int idx  = i * 512 + tid;
            int row  = idx / 24;
            int slot = idx - row * 24;
            int ss   = slot ^ (row & 7);
            const char* src = Kp + (long)(kv0 + row) * 384 + ss * 16;
            __builtin_amdgcn_global_load_lds((GV*)src, (LV*)(kbuf + idx * 16), 16, 0, 0);
        }
        // stage V^T tile [128][64] (1024 chunks)
#pragma unroll
        for (int i = 0; i < 2; ++i) {
            int idx  = i * 512 + tid;
            int row  = idx >> 3;
            int slot = idx & 7;
            int ss   = slot ^ (row & 7);
            const char* src = Vp + (long)row * (SS * 2) + kv0 * 2 + ss * 16;
            __builtin_amdgcn_global_load_lds((GV*)src, (LV*)(vbuf + idx * 16), 16, 0, 0);
        }
        __syncthreads();                 // staged data visible
        if (kv0 <= qa_min + 15)          // wave-uniform: skip fully-masked tiles
            attn_tile64(kbuf, vbuf, pw, qf, accv, ms, ls, kv0, qa, ql, kg, lane);
    }
    // ---- epilogue ----
    float li[4];
#pragma unroll
    for (int r = 0; r < 4; ++r)
        li[r] = 1.0f / __shfl(ls, (lane & 48) + kg * 4 + r);
#pragma unroll
    for (int v8 = 0; v8 < 8; ++v8)
#pragma unroll
        for (int r = 0; r < 4; ++r) {
            float o = accv[v8][r] * li[r];
            long row = (long)b * SS + qa_min + kg * 4 + r;
            ao[row * (long)(HH * VD) + h * VD + v8 * 16 + ql] = (bfu)f2bf(o);
        }
}

// ---------------- workspace layout (bytes) ----------------
#define O_XB   0L                     // x bf16 33,554,432      (later: vt alias)
#define O_WQ   33554432L              // wq bf16 12,582,912 (scaled by SCL2)
#define O_WA   46137344L              // wkv_a padded 2,621,440 (contiguous after wq)
#define O_WB   48758784L              // wkv_b 4,194,304
#define O_WO   52953088L              // wo 8,388,608
#define O_P1   61341696L              // merged proj1 out 8192x3712 bf16 = 60,817,408
#define O_QR   122159104L             // rope'd q 50,331,648
#define O_KVC  172490752L             // kv_c 8,388,608
#define O_KPE  180879360L             // k_pe 1,048,576
#define O_AO   181927936L             // attn out 33,554,432
#define WS_NEED 215482368L
// vpack (8192x2048 bf16 = 33,554,432 B) lives in d_out (67,108,864 B)
// kall (50,331,648 B) aliases O_P1 after rope_q/rms_rope consume it

extern "C" void kernel_launch(void* const* d_in, const int* in_sizes, int n_in,
                              void* d_out, int out_size, void* d_ws, size_t ws_size,
                              hipStream_t stream) {
    const float* x      = (const float*)d_in[0];
    const float* wq     = (const float*)d_in[1];
    const float* wkv_a  = (const float*)d_in[2];
    const float* kvnw   = (const float*)d_in[3];
    const float* wkv_b  = (const float*)d_in[4];
    const float* wo     = (const float*)d_in[5];
    const float* fcos   = (const float*)d_in[6];
    const float* fsin   = (const float*)d_in[7];
    if (ws_size < (size_t)WS_NEED) return;

    char* ws = (char*)d_ws;
    bfu* xb   = (bfu*)(ws + O_XB);
    bfu* wqb  = (bfu*)(ws + O_WQ);
    bfu* wab  = (bfu*)(ws + O_WA);
    bfu* wbb  = (bfu*)(ws + O_WB);
    bfu* wob  = (bfu*)(ws + O_WO);
    bfu* p1   = (bfu*)(ws + O_P1);
    bfu* qr   = (bfu*)(ws + O_QR);
    bfu* kvc  = (bfu*)(ws + O_KVC);
    bfu* kpe  = (bfu*)(ws + O_KPE);
    bfu* ao   = (bfu*)(ws + O_AO);
    bfu* kall = p1;                   // alias (p1 dead after rope_q + rms_rope)
    bfu* vt   = xb;                   // alias (xb dead after proj1 GEMM)
    bfu* vpack = (bfu*)d_out;         // alias (consumed before final GEMM)

    // 1. casts
    cast_f32_bf16<<<16384, 256, 0, stream>>>(x, xb, 16777216L, 16777216L);
    cast_weights<<<13568, 256, 0, stream>>>(wq, wkv_a, wkv_b, wo, wqb, wab, wbb, wob);

    // 2. merged projection: [q | kv_a] in one GEMM (wqb/wab contiguous, N=3712)
    gemm_bt<0><<<dim3(29, 64), 256, 0, stream>>>(xb, wqb, p1, nullptr, NP1, DD);

    // 3. rope / rmsnorm (read from p1)
    rope_q<<<12288, 256, 0, stream>>>(p1, qr, fcos, fsin);
    rms_rope_kv<<<ROWS, 256, 0, stream>>>(p1, kvnw, kvc, kpe, fcos, fsin);

    // 4. kv_b projection: nope -> kall (direct), v -> vpack (d_out scratch)
    gemm_bt<2><<<dim3(32, 64), 256, 0, stream>>>(kvc, wbb, vpack, kall, HH * 256, KVR);

    // 5. k_pe fill + V transpose
    pe_fill<<<4096, 256, 0, stream>>>(kpe, kall);
    transpose_v2<<<2048, 256, 0, stream>>>(vpack, vt);

    // 6. attention (1024 blocks x 512 threads: 64 bh x 16 q-tiles, 8 waves/block)
    attn<<<1024, 512, 0, stream>>>(qr, kall, vt, ao);

    // 7. output projection (fp32 out)
    gemm_bt<1><<<dim3(16, 64), 256, 0, stream>>>(ao, wob, d_out, nullptr, DD, HH * VD);
}